// Round 1
// baseline (807.463 us; speedup 1.0000x reference)
//
#include <hip/hip_runtime.h>
#include <stdint.h>

#define T_TOK 8192
#define DDIM  1024
#define FDIM  4096
#define NEXP  8
#define BM 128
#define BN 128
#define BK 32
#define LDK (BK + 8)   // padded LDS leading dim (keeps frag reads ~2-way conflicts = free)
#define MAX_MT (T_TOK / BM + NEXP)   // worst-case sum of per-expert M-tiles = 72

typedef __attribute__((ext_vector_type(8))) short bf16x8;
typedef __attribute__((ext_vector_type(8))) unsigned short u16x8;
typedef __attribute__((ext_vector_type(4))) float f32x4;

__device__ __forceinline__ unsigned short f2bf(float f) {
    union { float f; unsigned u; } v; v.f = f;
    unsigned u = v.u;
    u += 0x7fffu + ((u >> 16) & 1u);   // round-to-nearest-even
    return (unsigned short)(u >> 16);
}

// ---------------- transpose + fp32->bf16 convert ----------------
// src: [E][R][C] fp32   dst: [E][C][R] bf16   grid: (C/32, R/32, E), 256 thr
__global__ __launch_bounds__(256) void transpose_bf16(
    const float* __restrict__ src, unsigned short* __restrict__ dst, int R, int C) {
    __shared__ float tile[32][33];
    int e = blockIdx.z;
    int c0 = blockIdx.x * 32, r0 = blockIdx.y * 32;
    int tx = threadIdx.x & 31, ty = threadIdx.x >> 5;   // ty in 0..7
    const float* s = src + (size_t)e * R * C;
    unsigned short* d = dst + (size_t)e * R * C;
#pragma unroll
    for (int i = 0; i < 4; i++)
        tile[ty + 8 * i][tx] = s[(size_t)(r0 + ty + 8 * i) * C + c0 + tx];
    __syncthreads();
#pragma unroll
    for (int i = 0; i < 4; i++)
        d[(size_t)(c0 + ty + 8 * i) * R + r0 + tx] = f2bf(tile[tx][ty + 8 * i]);
}

// ---------------- router + layernorm ----------------
// one block per token; 256 threads, each owns 4 of the 1024 dims
__global__ __launch_bounds__(256) void router_ln(
    const float* __restrict__ x, const float* __restrict__ Wr, const float* __restrict__ br,
    const float* __restrict__ lng, const float* __restrict__ lnb,
    unsigned short* __restrict__ xn, float* __restrict__ gate,
    int* __restrict__ expert, int* __restrict__ counts) {
    int t = blockIdx.x, tid = threadIdx.x;
    const float4* xv4 = (const float4*)(x + (size_t)t * DDIM);
    float4 xv = xv4[tid];
    float s  = xv.x + xv.y + xv.z + xv.w;
    float sq = xv.x * xv.x + xv.y * xv.y + xv.z * xv.z + xv.w * xv.w;
    float lg[8] = {0, 0, 0, 0, 0, 0, 0, 0};
    const float4* wr4 = (const float4*)Wr;
    int d0 = tid * 4;
    const float* xr = (const float*)&xv;
#pragma unroll
    for (int r = 0; r < 4; r++) {
        float4 w0 = wr4[(d0 + r) * 2];
        float4 w1 = wr4[(d0 + r) * 2 + 1];
        lg[0] += xr[r] * w0.x; lg[1] += xr[r] * w0.y; lg[2] += xr[r] * w0.z; lg[3] += xr[r] * w0.w;
        lg[4] += xr[r] * w1.x; lg[5] += xr[r] * w1.y; lg[6] += xr[r] * w1.z; lg[7] += xr[r] * w1.w;
    }
#pragma unroll
    for (int o = 32; o > 0; o >>= 1) {
        s += __shfl_down(s, o); sq += __shfl_down(sq, o);
#pragma unroll
        for (int e = 0; e < 8; e++) lg[e] += __shfl_down(lg[e], o);
    }
    __shared__ float red[4][10];
    __shared__ float bc[2];
    int lane = tid & 63, wv = tid >> 6;
    if (lane == 0) {
        red[wv][0] = s; red[wv][1] = sq;
#pragma unroll
        for (int e = 0; e < 8; e++) red[wv][2 + e] = lg[e];
    }
    __syncthreads();
    if (tid == 0) {
        float S = 0, SQ = 0, L[8] = {0, 0, 0, 0, 0, 0, 0, 0};
        for (int w = 0; w < 4; w++) {
            S += red[w][0]; SQ += red[w][1];
            for (int e = 0; e < 8; e++) L[e] += red[w][2 + e];
        }
        float mu = S * (1.f / DDIM);
        float var = SQ * (1.f / DDIM) - mu * mu;
        float rstd = rsqrtf(var + 1e-5f);
        int best = 0; float bl = -3.4e38f;
        for (int e = 0; e < 8; e++) {
            float l = L[e] + br[e];
            L[e] = l;
            if (l > bl) { bl = l; best = e; }   // strict > keeps first occurrence (jnp.argmax)
        }
        float den = 0;
        for (int e = 0; e < 8; e++) den += __expf(L[e] - bl);
        gate[t] = 1.f / den;        // max softmax prob
        expert[t] = best;
        atomicAdd(&counts[best], 1);
        bc[0] = mu; bc[1] = rstd;
    }
    __syncthreads();
    float mu = bc[0], rstd = bc[1];
    float4 gg = ((const float4*)lng)[tid];
    float4 bb = ((const float4*)lnb)[tid];
    ushort4 o;
    o.x = f2bf((xv.x - mu) * rstd * gg.x + bb.x);
    o.y = f2bf((xv.y - mu) * rstd * gg.y + bb.y);
    o.z = f2bf((xv.z - mu) * rstd * gg.z + bb.z);
    o.w = f2bf((xv.w - mu) * rstd * gg.w + bb.w);
    *(ushort4*)(xn + (size_t)t * DDIM + d0) = o;
}

// ---------------- tiny scan ----------------
__global__ void scan_offsets(const int* __restrict__ counts, int* __restrict__ offs) {
    if (threadIdx.x == 0) {
        int a = 0;
        for (int e = 0; e < NEXP; e++) { offs[e] = a; a += counts[e]; }
    }
}

// ---------------- scatter tokens into per-expert lists ----------------
__global__ __launch_bounds__(256) void scatter_perm(
    const int* __restrict__ expert, const int* __restrict__ offs,
    int* __restrict__ fill, int* __restrict__ perm) {
    int t = blockIdx.x * 256 + threadIdx.x;
    int e = expert[t];
    int p = atomicAdd(&fill[e], 1);
    perm[offs[e] + p] = t;
}

// ---------------- grouped GEMM ----------------
// MODE 0: h = relu(xn @ W1[e] + b1[e])  A=[T,K=1024] Bt=[E][N=4096][K] -> Hout bf16
// MODE 1: y = (h @ W2[e] + b2[e])*gate  A=[T,K=4096] Bt=[E][N=1024][K] -> Yout f32
template <int MODE>
__global__ __launch_bounds__(256) void gemm_grouped(
    const unsigned short* __restrict__ A, const unsigned short* __restrict__ Bt,
    const float* __restrict__ bias, unsigned short* __restrict__ Hout,
    float* __restrict__ Yout, const float* __restrict__ gate,
    const int* __restrict__ perm, const int* __restrict__ counts,
    const int* __restrict__ offs, int K, int N) {
    // map blockIdx.x -> (expert, local M-tile)
    int rem = blockIdx.x;
    int e = 0; bool found = false;
    for (e = 0; e < NEXP; e++) {
        int mt = (counts[e] + (BM - 1)) >> 7;
        if (rem < mt) { found = true; break; }
        rem -= mt;
    }
    if (!found) return;
    int cnt = counts[e];
    int off = offs[e];
    int mbase = rem << 7;
    int mrem = cnt - mbase;       // rows < mrem are valid
    int n0 = blockIdx.y << 7;

    __shared__ __align__(16) unsigned short Alds[BM * LDK];
    __shared__ __align__(16) unsigned short Blds[BN * LDK];

    int tid = threadIdx.x;
    int r0 = tid >> 2, sg = tid & 3;   // each thread stages rows r0 and r0+64, 8 bf16 seg sg
    size_t arow[2]; bool avalid[2]; size_t brow[2]; int lds_off[2];
#pragma unroll
    for (int p = 0; p < 2; p++) {
        int r = r0 + 64 * p;
        avalid[p] = (r < mrem);
        int t = avalid[p] ? perm[off + mbase + r] : 0;
        arow[p] = (size_t)t * K + sg * 8;
        brow[p] = ((size_t)e * N + n0 + r) * K + sg * 8;
        lds_off[p] = r * LDK + sg * 8;
    }

    int lane = tid & 63, wave = tid >> 6;
    int wr = (wave >> 1) * 64, wc = (wave & 1) * 64;
    int q = lane >> 4, l16 = lane & 15;

    f32x4 acc[4][4] = {};

    for (int k0 = 0; k0 < K; k0 += BK) {
#pragma unroll
        for (int p = 0; p < 2; p++) {
            u16x8 av = {0, 0, 0, 0, 0, 0, 0, 0};
            if (avalid[p]) av = *(const u16x8*)(A + arow[p] + k0);
            *(u16x8*)&Alds[lds_off[p]] = av;
            *(u16x8*)&Blds[lds_off[p]] = *(const u16x8*)(Bt + brow[p] + k0);
        }
        __syncthreads();
        bf16x8 af[4], bfr[4];
#pragma unroll
        for (int i = 0; i < 4; i++)
            af[i] = *(const bf16x8*)&Alds[(wr + i * 16 + l16) * LDK + q * 8];
#pragma unroll
        for (int j = 0; j < 4; j++)
            bfr[j] = *(const bf16x8*)&Blds[(wc + j * 16 + l16) * LDK + q * 8];
#pragma unroll
        for (int i = 0; i < 4; i++)
#pragma unroll
            for (int j = 0; j < 4; j++)
                acc[i][j] = __builtin_amdgcn_mfma_f32_16x16x32_bf16(af[i], bfr[j], acc[i][j], 0, 0, 0);
        __syncthreads();
    }

    // epilogue: D layout col = lane&15, row = quad*4 + reg (verified m89/m91)
    float bs[4];
#pragma unroll
    for (int j = 0; j < 4; j++) bs[j] = bias[(size_t)e * N + n0 + wc + j * 16 + l16];
#pragma unroll
    for (int i = 0; i < 4; i++) {
#pragma unroll
        for (int r = 0; r < 4; r++) {
            int lrow = wr + i * 16 + q * 4 + r;
            if (lrow < mrem) {
                int t = perm[off + mbase + lrow];
                if (MODE == 0) {
                    unsigned short* hp = Hout + (size_t)t * N + n0 + wc + l16;
#pragma unroll
                    for (int j = 0; j < 4; j++) {
                        float v = acc[i][j][r] + bs[j];
                        hp[j * 16] = f2bf(fmaxf(v, 0.f));
                    }
                } else {
                    float gt = gate[t];
                    float* yp = Yout + (size_t)t * N + n0 + wc + l16;
#pragma unroll
                    for (int j = 0; j < 4; j++)
                        yp[j * 16] = (acc[i][j][r] + bs[j]) * gt;
                }
            }
        }
    }
}

extern "C" void kernel_launch(void* const* d_in, const int* in_sizes, int n_in,
                              void* d_out, int out_size, void* d_ws, size_t ws_size,
                              hipStream_t stream) {
    const float* x   = (const float*)d_in[0];
    const float* Wr  = (const float*)d_in[1];
    const float* br  = (const float*)d_in[2];
    const float* lng = (const float*)d_in[3];
    const float* lnb = (const float*)d_in[4];
    const float* W1  = (const float*)d_in[5];
    const float* b1  = (const float*)d_in[6];
    const float* W2  = (const float*)d_in[7];
    const float* b2  = (const float*)d_in[8];
    float* out = (float*)d_out;

    char* ws = (char*)d_ws;
    size_t o = 0;
    unsigned short* W1t = (unsigned short*)(ws + o); o += (size_t)NEXP * DDIM * FDIM * 2;  // [E][F][D]
    unsigned short* W2t = (unsigned short*)(ws + o); o += (size_t)NEXP * DDIM * FDIM * 2;  // [E][D][F]
    unsigned short* xn  = (unsigned short*)(ws + o); o += (size_t)T_TOK * DDIM * 2;        // [T][D]
    unsigned short* h   = (unsigned short*)(ws + o); o += (size_t)T_TOK * FDIM * 2;        // [T][F]
    float* gate = (float*)(ws + o); o += (size_t)T_TOK * 4;
    int* expert = (int*)(ws + o);   o += (size_t)T_TOK * 4;
    int* perm   = (int*)(ws + o);   o += (size_t)T_TOK * 4;
    int* meta   = (int*)(ws + o);   // counts[8], offs[8], fill[8]
    int* counts = meta;
    int* offs   = meta + 8;
    int* fill   = meta + 16;

    hipMemsetAsync(meta, 0, 32 * sizeof(int), stream);

    transpose_bf16<<<dim3(FDIM / 32, DDIM / 32, NEXP), 256, 0, stream>>>(W1, W1t, DDIM, FDIM);
    transpose_bf16<<<dim3(DDIM / 32, FDIM / 32, NEXP), 256, 0, stream>>>(W2, W2t, FDIM, DDIM);
    router_ln<<<T_TOK, 256, 0, stream>>>(x, Wr, br, lng, lnb, xn, gate, expert, counts);
    scan_offsets<<<1, 64, 0, stream>>>(counts, offs);
    scatter_perm<<<T_TOK / 256, 256, 0, stream>>>(expert, offs, fill, perm);
    gemm_grouped<0><<<dim3(MAX_MT, FDIM / BN), 256, 0, stream>>>(
        xn, W1t, b1, h, nullptr, nullptr, perm, counts, offs, DDIM, FDIM);
    gemm_grouped<1><<<dim3(MAX_MT, DDIM / BN), 256, 0, stream>>>(
        h, W2t, b2, nullptr, out, gate, perm, counts, offs, FDIM, DDIM);
}

// Round 2
// 746.096 us; speedup vs baseline: 1.0823x; 1.0823x over previous
//
#include <hip/hip_runtime.h>
#include <stdint.h>

#define T_TOK 8192
#define DDIM  1024
#define FDIM  4096
#define NEXP  8
#define BM 128
#define BN 128
#define BK 32
#define MAX_MT (T_TOK / BM + NEXP)   // worst-case sum of per-expert M-tiles = 72

typedef __attribute__((ext_vector_type(8))) short bf16x8;
typedef __attribute__((ext_vector_type(8))) unsigned short u16x8;
typedef __attribute__((ext_vector_type(4))) float f32x4;

__device__ __forceinline__ unsigned short f2bf(float f) {
    union { float f; unsigned u; } v; v.f = f;
    unsigned u = v.u;
    u += 0x7fffu + ((u >> 16) & 1u);   // round-to-nearest-even
    return (unsigned short)(u >> 16);
}

// async global->LDS, 16 B per lane. LDS dest is wave-uniform base; lane l
// lands at base + l*16 (m97/m104-verified semantics).
__device__ __forceinline__ void async16(const void* g, void* l) {
    __builtin_amdgcn_global_load_lds(
        (const __attribute__((address_space(1))) unsigned int*)g,
        (__attribute__((address_space(3))) unsigned int*)l, 16, 0, 0);
}

// ---------------- transpose + fp32->bf16 convert ----------------
// src: [E][R][C] fp32   dst: [E][C][R] bf16   grid: (C/64, R/64, E), 256 thr
__global__ __launch_bounds__(256) void transpose_bf16(
    const float* __restrict__ src, unsigned short* __restrict__ dst, int R, int C) {
    __shared__ float tile[64][65];
    int e = blockIdx.z;
    int c0 = blockIdx.x * 64, r0 = blockIdx.y * 64;
    const float* s = src + (size_t)e * R * C;
    unsigned short* d = dst + (size_t)e * R * C;
    int tid = threadIdx.x;
    int lr = tid >> 4;            // 0..15
    int lc = (tid & 15) * 4;      // 0..60
#pragma unroll
    for (int i = 0; i < 4; i++) {
        float4 v = *(const float4*)&s[(size_t)(r0 + lr + i * 16) * C + c0 + lc];
        tile[lr + i * 16][lc + 0] = v.x;
        tile[lr + i * 16][lc + 1] = v.y;
        tile[lr + i * 16][lc + 2] = v.z;
        tile[lr + i * 16][lc + 3] = v.w;
    }
    __syncthreads();
#pragma unroll
    for (int i = 0; i < 2; i++) {
        int idx = tid + i * 256;
        int drow = idx >> 3;      // dst row = src col, 0..63
        int seg  = idx & 7;       // 8 bf16 per seg
        u16x8 o;
#pragma unroll
        for (int j = 0; j < 8; j++) o[j] = f2bf(tile[seg * 8 + j][drow]);
        *(u16x8*)&d[(size_t)(c0 + drow) * R + r0 + seg * 8] = o;
    }
}

// ---------------- router + layernorm ----------------
__global__ __launch_bounds__(256) void router_ln(
    const float* __restrict__ x, const float* __restrict__ Wr, const float* __restrict__ br,
    const float* __restrict__ lng, const float* __restrict__ lnb,
    unsigned short* __restrict__ xn, float* __restrict__ gate,
    int* __restrict__ expert, int* __restrict__ counts) {
    int t = blockIdx.x, tid = threadIdx.x;
    const float4* xv4 = (const float4*)(x + (size_t)t * DDIM);
    float4 xv = xv4[tid];
    float s  = xv.x + xv.y + xv.z + xv.w;
    float sq = xv.x * xv.x + xv.y * xv.y + xv.z * xv.z + xv.w * xv.w;
    float lg[8] = {0, 0, 0, 0, 0, 0, 0, 0};
    const float4* wr4 = (const float4*)Wr;
    int d0 = tid * 4;
    const float* xr = (const float*)&xv;
#pragma unroll
    for (int r = 0; r < 4; r++) {
        float4 w0 = wr4[(d0 + r) * 2];
        float4 w1 = wr4[(d0 + r) * 2 + 1];
        lg[0] += xr[r] * w0.x; lg[1] += xr[r] * w0.y; lg[2] += xr[r] * w0.z; lg[3] += xr[r] * w0.w;
        lg[4] += xr[r] * w1.x; lg[5] += xr[r] * w1.y; lg[6] += xr[r] * w1.z; lg[7] += xr[r] * w1.w;
    }
#pragma unroll
    for (int o = 32; o > 0; o >>= 1) {
        s += __shfl_down(s, o); sq += __shfl_down(sq, o);
#pragma unroll
        for (int e = 0; e < 8; e++) lg[e] += __shfl_down(lg[e], o);
    }
    __shared__ float red[4][10];
    __shared__ float bc[2];
    int lane = tid & 63, wv = tid >> 6;
    if (lane == 0) {
        red[wv][0] = s; red[wv][1] = sq;
#pragma unroll
        for (int e = 0; e < 8; e++) red[wv][2 + e] = lg[e];
    }
    __syncthreads();
    if (tid == 0) {
        float S = 0, SQ = 0, L[8] = {0, 0, 0, 0, 0, 0, 0, 0};
        for (int w = 0; w < 4; w++) {
            S += red[w][0]; SQ += red[w][1];
            for (int e = 0; e < 8; e++) L[e] += red[w][2 + e];
        }
        float mu = S * (1.f / DDIM);
        float var = SQ * (1.f / DDIM) - mu * mu;
        float rstd = rsqrtf(var + 1e-5f);
        int best = 0; float bl = -3.4e38f;
        for (int e = 0; e < 8; e++) {
            float l = L[e] + br[e];
            L[e] = l;
            if (l > bl) { bl = l; best = e; }   // strict > == jnp.argmax first-max
        }
        float den = 0;
        for (int e = 0; e < 8; e++) den += __expf(L[e] - bl);
        gate[t] = 1.f / den;
        expert[t] = best;
        atomicAdd(&counts[best], 1);
        bc[0] = mu; bc[1] = rstd;
    }
    __syncthreads();
    float mu = bc[0], rstd = bc[1];
    float4 gg = ((const float4*)lng)[tid];
    float4 bb = ((const float4*)lnb)[tid];
    ushort4 o;
    o.x = f2bf((xv.x - mu) * rstd * gg.x + bb.x);
    o.y = f2bf((xv.y - mu) * rstd * gg.y + bb.y);
    o.z = f2bf((xv.z - mu) * rstd * gg.z + bb.z);
    o.w = f2bf((xv.w - mu) * rstd * gg.w + bb.w);
    *(ushort4*)(xn + (size_t)t * DDIM + d0) = o;
}

// ---------------- scatter tokens into per-expert lists (scan folded in) ----
__global__ __launch_bounds__(256) void scatter_perm(
    const int* __restrict__ expert, const int* __restrict__ counts,
    int* __restrict__ fill, int* __restrict__ perm) {
    __shared__ int offs_s[NEXP];
    if (threadIdx.x < NEXP) {
        int o = 0;
        for (int i = 0; i < (int)threadIdx.x; i++) o += counts[i];
        offs_s[threadIdx.x] = o;
    }
    __syncthreads();
    int t = blockIdx.x * 256 + threadIdx.x;
    int e = expert[t];
    int p = atomicAdd(&fill[e], 1);
    perm[offs_s[e] + p] = t;
}

// ---------------- grouped GEMM (m97 structure) ----------------
// MODE 0: h = relu(xn @ W1t[e]^T + b1[e])   A=[T,K=1024]  Bt=[E][N=4096][K]
// MODE 1: y = (h @ W2t[e]^T + b2[e])*gate   A=[T,K=4096]  Bt=[E][N=1024][K]
template <int MODE>
__global__ __launch_bounds__(256) void gemm_grouped(
    const unsigned short* __restrict__ A, const unsigned short* __restrict__ Bt,
    const float* __restrict__ bias, unsigned short* __restrict__ Hout,
    float* __restrict__ Yout, const float* __restrict__ gate,
    const int* __restrict__ perm, const int* __restrict__ counts,
    int K, int N) {
    // map blockIdx.x -> (expert, local M-tile); prefix-sum offs on the fly
    int rem = blockIdx.x;
    int e, off = 0, cnt = 0; bool found = false;
    for (e = 0; e < NEXP; e++) {
        cnt = counts[e];
        int mt = (cnt + (BM - 1)) >> 7;
        if (rem < mt) { found = true; break; }
        rem -= mt; off += cnt;
    }
    if (!found) return;
    int mbase = rem << 7;
    int mrem = cnt - mbase;       // rows < mrem are valid
    int n0 = blockIdx.y << 7;

    // unpadded: row stride 32 bf16 = 64 B (required by global_load_lds layout)
    __shared__ __align__(16) unsigned short Alds[BM * BK];
    __shared__ __align__(16) unsigned short Blds[BN * BK];

    int tid = threadIdx.x;
    int lane = tid & 63, wave = tid >> 6;
    int grow = lane >> 2;         // row within 16-row wave group
    int seg  = lane & 3;          // 16-B segment within 64-B row

    // per-lane global pointers (A gathers via perm; invalid tail rows clamp
    // to row 0 — their C rows are never stored, MFMA rows are independent)
    const unsigned short* ag[2];
    const unsigned short* bg[2];
    unsigned short* al[2];
    unsigned short* bl[2];
#pragma unroll
    for (int p = 0; p < 2; p++) {
        int r = p * 64 + wave * 16 + grow;
        int rr = (r < mrem) ? r : 0;
        int t = perm[off + mbase + rr];
        ag[p] = A + (size_t)t * K + seg * 8;
        bg[p] = Bt + ((size_t)e * N + n0 + r) * K + seg * 8;
        al[p] = &Alds[(p * 64 + wave * 16) * BK];   // wave-uniform LDS base
        bl[p] = &Blds[(p * 64 + wave * 16) * BK];
    }

    int wr = (wave >> 1) * 64, wc = (wave & 1) * 64;
    int q = lane >> 4, l16 = lane & 15;

    f32x4 acc[4][4] = {};

    for (int k0 = 0; k0 < K; k0 += BK) {
#pragma unroll
        for (int p = 0; p < 2; p++) {
            async16(ag[p] + k0, al[p]);
            async16(bg[p] + k0, bl[p]);
        }
        __syncthreads();
        bf16x8 af[4], bfr[4];
#pragma unroll
        for (int i = 0; i < 4; i++)
            af[i] = *(const bf16x8*)&Alds[(wr + i * 16 + l16) * BK + q * 8];
#pragma unroll
        for (int j = 0; j < 4; j++)
            bfr[j] = *(const bf16x8*)&Blds[(wc + j * 16 + l16) * BK + q * 8];
#pragma unroll
        for (int i = 0; i < 4; i++)
#pragma unroll
            for (int j = 0; j < 4; j++)
                acc[i][j] = __builtin_amdgcn_mfma_f32_16x16x32_bf16(af[i], bfr[j], acc[i][j], 0, 0, 0);
        __syncthreads();
    }

    // epilogue: D layout col = lane&15, row = quad*4 + reg (m89/m91)
    float bs[4];
#pragma unroll
    for (int j = 0; j < 4; j++) bs[j] = bias[(size_t)e * N + n0 + wc + j * 16 + l16];
#pragma unroll
    for (int i = 0; i < 4; i++) {
#pragma unroll
        for (int r = 0; r < 4; r++) {
            int lrow = wr + i * 16 + q * 4 + r;
            if (lrow < mrem) {
                int t = perm[off + mbase + lrow];
                if (MODE == 0) {
                    unsigned short* hp = Hout + (size_t)t * N + n0 + wc + l16;
#pragma unroll
                    for (int j = 0; j < 4; j++) {
                        float v = acc[i][j][r] + bs[j];
                        hp[j * 16] = f2bf(fmaxf(v, 0.f));
                    }
                } else {
                    float gt = gate[t];
                    float* yp = Yout + (size_t)t * N + n0 + wc + l16;
#pragma unroll
                    for (int j = 0; j < 4; j++)
                        yp[j * 16] = (acc[i][j][r] + bs[j]) * gt;
                }
            }
        }
    }
}

extern "C" void kernel_launch(void* const* d_in, const int* in_sizes, int n_in,
                              void* d_out, int out_size, void* d_ws, size_t ws_size,
                              hipStream_t stream) {
    const float* x   = (const float*)d_in[0];
    const float* Wr  = (const float*)d_in[1];
    const float* br  = (const float*)d_in[2];
    const float* lng = (const float*)d_in[3];
    const float* lnb = (const float*)d_in[4];
    const float* W1  = (const float*)d_in[5];
    const float* b1  = (const float*)d_in[6];
    const float* W2  = (const float*)d_in[7];
    const float* b2  = (const float*)d_in[8];
    float* out = (float*)d_out;

    char* ws = (char*)d_ws;
    size_t o = 0;
    unsigned short* W1t = (unsigned short*)(ws + o); o += (size_t)NEXP * DDIM * FDIM * 2;  // [E][F][D]
    unsigned short* W2t = (unsigned short*)(ws + o); o += (size_t)NEXP * DDIM * FDIM * 2;  // [E][D][F]
    unsigned short* xn  = (unsigned short*)(ws + o); o += (size_t)T_TOK * DDIM * 2;        // [T][D]
    unsigned short* h   = (unsigned short*)(ws + o); o += (size_t)T_TOK * FDIM * 2;        // [T][F]
    float* gate = (float*)(ws + o); o += (size_t)T_TOK * 4;
    int* expert = (int*)(ws + o);   o += (size_t)T_TOK * 4;
    int* perm   = (int*)(ws + o);   o += (size_t)T_TOK * 4;
    int* meta   = (int*)(ws + o);   // counts[8], fill[8]
    int* counts = meta;
    int* fill   = meta + 8;

    hipMemsetAsync(meta, 0, 16 * sizeof(int), stream);

    transpose_bf16<<<dim3(FDIM / 64, DDIM / 64, NEXP), 256, 0, stream>>>(W1, W1t, DDIM, FDIM);
    transpose_bf16<<<dim3(DDIM / 64, FDIM / 64, NEXP), 256, 0, stream>>>(W2, W2t, FDIM, DDIM);
    router_ln<<<T_TOK, 256, 0, stream>>>(x, Wr, br, lng, lnb, xn, gate, expert, counts);
    scatter_perm<<<T_TOK / 256, 256, 0, stream>>>(expert, counts, fill, perm);
    gemm_grouped<0><<<dim3(MAX_MT, FDIM / BN), 256, 0, stream>>>(
        xn, W1t, b1, h, nullptr, nullptr, perm, counts, DDIM, FDIM);
    gemm_grouped<1><<<dim3(MAX_MT, DDIM / BN), 256, 0, stream>>>(
        h, W2t, b2, nullptr, out, gate, perm, counts, FDIM, DDIM);
}

// Round 3
// 714.439 us; speedup vs baseline: 1.1302x; 1.0443x over previous
//
#include <hip/hip_runtime.h>
#include <stdint.h>

#define T_TOK 8192
#define DDIM  1024
#define FDIM  4096
#define NEXP  8
#define BM 128
#define BK 32
#define MAX_MT (T_TOK / BM + NEXP)   // worst-case sum of per-expert M-tiles = 72

typedef __attribute__((ext_vector_type(8))) short bf16x8;
typedef __attribute__((ext_vector_type(8))) unsigned short u16x8;
typedef __attribute__((ext_vector_type(4))) float f32x4;

__device__ __forceinline__ unsigned short f2bf(float f) {
    union { float f; unsigned u; } v; v.f = f;
    unsigned u = v.u;
    u += 0x7fffu + ((u >> 16) & 1u);   // round-to-nearest-even
    return (unsigned short)(u >> 16);
}

__device__ __forceinline__ void async16(const void* g, void* l) {
    __builtin_amdgcn_global_load_lds(
        (const __attribute__((address_space(1))) unsigned int*)g,
        (__attribute__((address_space(3))) unsigned int*)l, 16, 0, 0);
}

// ================== fused prep: router+LN (blocks 0..8191),
//                    W1 transpose (8192..16383), W2 transpose (16384..24575)
__global__ __launch_bounds__(256) void prep(
    const float* __restrict__ x, const float* __restrict__ Wr, const float* __restrict__ br,
    const float* __restrict__ lng, const float* __restrict__ lnb,
    const float* __restrict__ W1, const float* __restrict__ W2,
    unsigned short* __restrict__ xn, unsigned short* __restrict__ W1t,
    unsigned short* __restrict__ W2t, float* __restrict__ gate,
    int* __restrict__ expert, int* __restrict__ counts) {
    __shared__ float smem[64 * 65];   // transpose tile; router reuses head
    int b = blockIdx.x, tid = threadIdx.x;

    if (b >= T_TOK) {
        // ---------- transpose + fp32->bf16 ----------
        int idx = b - T_TOK;
        const float* src; unsigned short* dst; int R, C, e, c0, r0;
        if (idx < 8192) {               // W1 [E][1024][4096] -> W1t [E][4096][1024]
            R = DDIM; C = FDIM;
            e = idx >> 10;
            c0 = (idx & 63) * 64; r0 = ((idx >> 6) & 15) * 64;
            src = W1; dst = W1t;
        } else {                        // W2 [E][4096][1024] -> W2t [E][1024][4096]
            idx -= 8192;
            R = FDIM; C = DDIM;
            e = idx >> 10;
            c0 = (idx & 15) * 64; r0 = ((idx >> 4) & 63) * 64;
            src = W2; dst = W2t;
        }
        const float* s = src + (size_t)e * R * C;
        unsigned short* d = dst + (size_t)e * R * C;
        float (*tile)[65] = (float(*)[65])smem;
        int lr = tid >> 4, lc = (tid & 15) * 4;
#pragma unroll
        for (int i = 0; i < 4; i++) {
            float4 v = *(const float4*)&s[(size_t)(r0 + lr + i * 16) * C + c0 + lc];
            tile[lr + i * 16][lc + 0] = v.x;
            tile[lr + i * 16][lc + 1] = v.y;
            tile[lr + i * 16][lc + 2] = v.z;
            tile[lr + i * 16][lc + 3] = v.w;
        }
        __syncthreads();
#pragma unroll
        for (int i = 0; i < 2; i++) {
            int ix = tid + i * 256;
            int drow = ix >> 3, seg = ix & 7;
            u16x8 o;
#pragma unroll
            for (int j = 0; j < 8; j++) o[j] = f2bf(tile[seg * 8 + j][drow]);
            *(u16x8*)&d[(size_t)(c0 + drow) * R + r0 + seg * 8] = o;
        }
        return;
    }

    // ---------- router + layernorm ----------
    int t = b;
    const float4* xv4 = (const float4*)(x + (size_t)t * DDIM);
    float4 xv = xv4[tid];
    float s  = xv.x + xv.y + xv.z + xv.w;
    float sq = xv.x * xv.x + xv.y * xv.y + xv.z * xv.z + xv.w * xv.w;
    float lg[8] = {0, 0, 0, 0, 0, 0, 0, 0};
    const float4* wr4 = (const float4*)Wr;
    int d0 = tid * 4;
    const float* xr = (const float*)&xv;
#pragma unroll
    for (int r = 0; r < 4; r++) {
        float4 w0 = wr4[(d0 + r) * 2];
        float4 w1 = wr4[(d0 + r) * 2 + 1];
        lg[0] += xr[r] * w0.x; lg[1] += xr[r] * w0.y; lg[2] += xr[r] * w0.z; lg[3] += xr[r] * w0.w;
        lg[4] += xr[r] * w1.x; lg[5] += xr[r] * w1.y; lg[6] += xr[r] * w1.z; lg[7] += xr[r] * w1.w;
    }
#pragma unroll
    for (int o = 32; o > 0; o >>= 1) {
        s += __shfl_down(s, o); sq += __shfl_down(sq, o);
#pragma unroll
        for (int e = 0; e < 8; e++) lg[e] += __shfl_down(lg[e], o);
    }
    float* red = smem;            // [4][10]
    float* bc = smem + 40;
    int lane = tid & 63, wv = tid >> 6;
    if (lane == 0) {
        red[wv * 10 + 0] = s; red[wv * 10 + 1] = sq;
#pragma unroll
        for (int e = 0; e < 8; e++) red[wv * 10 + 2 + e] = lg[e];
    }
    __syncthreads();
    if (tid == 0) {
        float S = 0, SQ = 0, L[8] = {0, 0, 0, 0, 0, 0, 0, 0};
        for (int w = 0; w < 4; w++) {
            S += red[w * 10 + 0]; SQ += red[w * 10 + 1];
            for (int e = 0; e < 8; e++) L[e] += red[w * 10 + 2 + e];
        }
        float mu = S * (1.f / DDIM);
        float var = SQ * (1.f / DDIM) - mu * mu;
        float rstd = rsqrtf(var + 1e-5f);
        int best = 0; float bl = -3.4e38f;
        for (int e = 0; e < 8; e++) {
            float l = L[e] + br[e];
            L[e] = l;
            if (l > bl) { bl = l; best = e; }   // strict > == jnp.argmax first-max
        }
        float den = 0;
        for (int e = 0; e < 8; e++) den += __expf(L[e] - bl);
        gate[t] = 1.f / den;
        expert[t] = best;
        atomicAdd(&counts[best], 1);
        bc[0] = mu; bc[1] = rstd;
    }
    __syncthreads();
    float mu = bc[0], rstd = bc[1];
    float4 gg = ((const float4*)lng)[tid];
    float4 bb = ((const float4*)lnb)[tid];
    ushort4 o;
    o.x = f2bf((xv.x - mu) * rstd * gg.x + bb.x);
    o.y = f2bf((xv.y - mu) * rstd * gg.y + bb.y);
    o.z = f2bf((xv.z - mu) * rstd * gg.z + bb.z);
    o.w = f2bf((xv.w - mu) * rstd * gg.w + bb.w);
    *(ushort4*)(xn + (size_t)t * DDIM + d0) = o;
}

// ---------------- scatter tokens into per-expert lists (scan folded in) ----
__global__ __launch_bounds__(256) void scatter_perm(
    const int* __restrict__ expert, const int* __restrict__ counts,
    int* __restrict__ fill, int* __restrict__ perm) {
    __shared__ int offs_s[NEXP];
    if (threadIdx.x < NEXP) {
        int o = 0;
        for (int i = 0; i < (int)threadIdx.x; i++) o += counts[i];
        offs_s[threadIdx.x] = o;
    }
    __syncthreads();
    int t = blockIdx.x * 256 + threadIdx.x;
    int e = expert[t];
    int p = atomicAdd(&fill[e], 1);
    perm[offs_s[e] + p] = t;
}

// ---------------- grouped GEMM (m97 structure) ----------------
// MODE 0: h_perm = relu(xn[perm] @ W1t[e]^T + b1[e])  128x128 tile, K=1024
// MODE 1: y[perm] = (h_perm @ W2t[e]^T + b2[e])*gate  128x64 tile,  K=4096
template <int MODE>
__global__ __launch_bounds__(256) void gemm_grouped(
    const unsigned short* __restrict__ A, const unsigned short* __restrict__ Bt,
    const float* __restrict__ bias, unsigned short* __restrict__ Hout,
    float* __restrict__ Yout, const float* __restrict__ gate,
    const int* __restrict__ perm, const int* __restrict__ counts,
    int K, int N) {
    constexpr int BN_ = (MODE == 0) ? 128 : 64;
    constexpr int AI  = (MODE == 0) ? 4 : 2;   // A frags / wave
    constexpr int BROWS = (MODE == 0) ? 2 : 1; // B staging rows / thread

    int rem = blockIdx.x;
    int e, off = 0, cnt = 0; bool found = false;
    for (e = 0; e < NEXP; e++) {
        cnt = counts[e];
        int mt = (cnt + (BM - 1)) >> 7;
        if (rem < mt) { found = true; break; }
        rem -= mt; off += cnt;
    }
    if (!found) return;
    int mbase = rem << 7;
    int mrem = cnt - mbase;
    int n0 = blockIdx.y * BN_;

    __shared__ __align__(16) unsigned short Alds[BM * BK];
    __shared__ __align__(16) unsigned short Blds[BN_ * BK];

    int tid = threadIdx.x;
    int lane = tid & 63, wave = tid >> 6;
    int grow = lane >> 2;         // row within 16-row wave group
    int seg  = lane & 3;          // 16-B segment within 64-B row

    const unsigned short* ag[2];
    unsigned short* al[2];
    const unsigned short* bg[BROWS];
    unsigned short* bl[BROWS];
#pragma unroll
    for (int p = 0; p < 2; p++) {
        int r = p * 64 + wave * 16 + grow;
        int rr = (r < mrem) ? r : 0;
        if (MODE == 0) {
            int t = perm[off + mbase + rr];          // gather token
            ag[p] = A + (size_t)t * K + seg * 8;
        } else {
            ag[p] = A + (size_t)(off + mbase + rr) * K + seg * 8;  // h is permuted
        }
        al[p] = &Alds[(p * 64 + wave * 16) * BK];
    }
#pragma unroll
    for (int p = 0; p < BROWS; p++) {
        int r = p * 64 + wave * 16 + grow;
        bg[p] = Bt + ((size_t)e * N + n0 + r) * K + seg * 8;
        bl[p] = &Blds[(p * 64 + wave * 16) * BK];
    }

    int wr = (MODE == 0) ? (wave >> 1) * 64 : wave * 32;
    int wc = (MODE == 0) ? (wave & 1) * 64 : 0;
    int q = lane >> 4, l16 = lane & 15;

    f32x4 acc[AI][4] = {};

    for (int k0 = 0; k0 < K; k0 += BK) {
#pragma unroll
        for (int p = 0; p < 2; p++) async16(ag[p] + k0, al[p]);
#pragma unroll
        for (int p = 0; p < BROWS; p++) async16(bg[p] + k0, bl[p]);
        __syncthreads();
        bf16x8 af[AI], bfr[4];
#pragma unroll
        for (int i = 0; i < AI; i++)
            af[i] = *(const bf16x8*)&Alds[(wr + i * 16 + l16) * BK + q * 8];
#pragma unroll
        for (int j = 0; j < 4; j++)
            bfr[j] = *(const bf16x8*)&Blds[(wc + j * 16 + l16) * BK + q * 8];
#pragma unroll
        for (int i = 0; i < AI; i++)
#pragma unroll
            for (int j = 0; j < 4; j++)
                acc[i][j] = __builtin_amdgcn_mfma_f32_16x16x32_bf16(af[i], bfr[j], acc[i][j], 0, 0, 0);
        __syncthreads();
    }

    // epilogue: D layout col = lane&15, row = quad*4 + reg (m89/m91)
    float bs[4];
#pragma unroll
    for (int j = 0; j < 4; j++) bs[j] = bias[(size_t)e * N + n0 + wc + j * 16 + l16];
#pragma unroll
    for (int i = 0; i < AI; i++) {
#pragma unroll
        for (int r = 0; r < 4; r++) {
            int lrow = wr + i * 16 + q * 4 + r;
            if (lrow < mrem) {
                if (MODE == 0) {
                    // store h in PERMUTED row order (contiguous for GEMM1)
                    unsigned short* hp = Hout + (size_t)(off + mbase + lrow) * N + n0 + wc + l16;
#pragma unroll
                    for (int j = 0; j < 4; j++) {
                        float v = acc[i][j][r] + bs[j];
                        hp[j * 16] = f2bf(fmaxf(v, 0.f));
                    }
                } else {
                    int t = perm[off + mbase + lrow];
                    float gt = gate[t];
                    float* yp = Yout + (size_t)t * N + n0 + wc + l16;
#pragma unroll
                    for (int j = 0; j < 4; j++)
                        yp[j * 16] = (acc[i][j][r] + bs[j]) * gt;
                }
            }
        }
    }
}

extern "C" void kernel_launch(void* const* d_in, const int* in_sizes, int n_in,
                              void* d_out, int out_size, void* d_ws, size_t ws_size,
                              hipStream_t stream) {
    const float* x   = (const float*)d_in[0];
    const float* Wr  = (const float*)d_in[1];
    const float* br  = (const float*)d_in[2];
    const float* lng = (const float*)d_in[3];
    const float* lnb = (const float*)d_in[4];
    const float* W1  = (const float*)d_in[5];
    const float* b1  = (const float*)d_in[6];
    const float* W2  = (const float*)d_in[7];
    const float* b2  = (const float*)d_in[8];
    float* out = (float*)d_out;

    char* ws = (char*)d_ws;
    size_t o = 0;
    unsigned short* W1t = (unsigned short*)(ws + o); o += (size_t)NEXP * DDIM * FDIM * 2;  // [E][F][D]
    unsigned short* W2t = (unsigned short*)(ws + o); o += (size_t)NEXP * DDIM * FDIM * 2;  // [E][D][F]
    unsigned short* xn  = (unsigned short*)(ws + o); o += (size_t)T_TOK * DDIM * 2;        // [T][D]
    unsigned short* h   = (unsigned short*)(ws + o); o += (size_t)T_TOK * FDIM * 2;        // [Tperm][F]
    float* gate = (float*)(ws + o); o += (size_t)T_TOK * 4;
    int* expert = (int*)(ws + o);   o += (size_t)T_TOK * 4;
    int* perm   = (int*)(ws + o);   o += (size_t)T_TOK * 4;
    int* meta   = (int*)(ws + o);   // counts[8], fill[8]
    int* counts = meta;
    int* fill   = meta + 8;

    hipMemsetAsync(meta, 0, 16 * sizeof(int), stream);

    prep<<<T_TOK + 16384, 256, 0, stream>>>(x, Wr, br, lng, lnb, W1, W2,
                                            xn, W1t, W2t, gate, expert, counts);
    scatter_perm<<<T_TOK / 256, 256, 0, stream>>>(expert, counts, fill, perm);
    gemm_grouped<0><<<dim3(MAX_MT, FDIM / 128), 256, 0, stream>>>(
        xn, W1t, b1, h, nullptr, nullptr, perm, counts, DDIM, FDIM);
    gemm_grouped<1><<<dim3(MAX_MT, DDIM / 64), 256, 0, stream>>>(
        h, W2t, b2, nullptr, out, gate, perm, counts, FDIM, DDIM);
}

// Round 4
// 658.395 us; speedup vs baseline: 1.2264x; 1.0851x over previous
//
#include <hip/hip_runtime.h>
#include <stdint.h>

#define T_TOK 8192
#define DDIM  1024
#define FDIM  4096
#define NEXP  8
#define BM 128
#define BK 32
#define MAX_MT (T_TOK / BM + NEXP)   // worst-case sum of per-expert M-tiles = 72

typedef __attribute__((ext_vector_type(8))) short bf16x8;
typedef __attribute__((ext_vector_type(8))) unsigned short u16x8;
typedef __attribute__((ext_vector_type(4))) float f32x4;

__device__ __forceinline__ unsigned short f2bf(float f) {
    union { float f; unsigned u; } v; v.f = f;
    unsigned u = v.u;
    u += 0x7fffu + ((u >> 16) & 1u);   // round-to-nearest-even
    return (unsigned short)(u >> 16);
}

__device__ __forceinline__ void async16(const void* g, void* l) {
    __builtin_amdgcn_global_load_lds(
        (const __attribute__((address_space(1))) unsigned int*)g,
        (__attribute__((address_space(3))) unsigned int*)l, 16, 0, 0);
}

// ============ init: zero meta + build WrT[8][1024] (replaces memset) =======
__global__ __launch_bounds__(256) void init_kernel(
    const float* __restrict__ Wr, float* __restrict__ WrT, int* __restrict__ meta) {
    int idx = blockIdx.x * 256 + threadIdx.x;   // 32 blocks x 256 = 8192
    if (idx < 16) meta[idx] = 0;
    float v = Wr[idx];                          // Wr[d][e], d=idx>>3, e=idx&7
    WrT[(idx & 7) * DDIM + (idx >> 3)] = v;
}

// ============ fused prep: blockIdx%3 == 0 router, 1 W1-transpose, 2 W2 =====
__global__ __launch_bounds__(256) void prep(
    const float* __restrict__ x, const float* __restrict__ WrT, const float* __restrict__ br,
    const float* __restrict__ lng, const float* __restrict__ lnb,
    const float* __restrict__ W1, const float* __restrict__ W2,
    unsigned short* __restrict__ xn, unsigned short* __restrict__ W1t,
    unsigned short* __restrict__ W2t, float* __restrict__ gate,
    int* __restrict__ expert, int* __restrict__ counts) {
    __shared__ float smem[64 * 65];
    int b = blockIdx.x, tid = threadIdx.x;
    int r3 = b % 3, q = b / 3;

    if (r3 != 0) {
        // ---------- transpose + fp32->bf16 ----------
        const float* src; unsigned short* dst; int R, C, e, c0, r0;
        if (r3 == 1) {                  // W1 [E][1024][4096] -> W1t [E][4096][1024]
            R = DDIM; C = FDIM;
            e = q >> 10;
            c0 = (q & 63) * 64; r0 = ((q >> 6) & 15) * 64;
            src = W1; dst = W1t;
        } else {                        // W2 [E][4096][1024] -> W2t [E][1024][4096]
            R = FDIM; C = DDIM;
            e = q >> 10;
            c0 = (q & 15) * 64; r0 = ((q >> 4) & 63) * 64;
            src = W2; dst = W2t;
        }
        const float* s = src + (size_t)e * R * C;
        unsigned short* d = dst + (size_t)e * R * C;
        float (*tile)[65] = (float(*)[65])smem;
        int lr = tid >> 4, lc = (tid & 15) * 4;
#pragma unroll
        for (int i = 0; i < 4; i++) {
            float4 v = *(const float4*)&s[(size_t)(r0 + lr + i * 16) * C + c0 + lc];
            tile[lr + i * 16][lc + 0] = v.x;
            tile[lr + i * 16][lc + 1] = v.y;
            tile[lr + i * 16][lc + 2] = v.z;
            tile[lr + i * 16][lc + 3] = v.w;
        }
        __syncthreads();
#pragma unroll
        for (int i = 0; i < 2; i++) {
            int ix = tid + i * 256;
            int drow = ix >> 3, seg = ix & 7;
            u16x8 o;
#pragma unroll
            for (int j = 0; j < 8; j++) o[j] = f2bf(tile[seg * 8 + j][drow]);
            *(u16x8*)&d[(size_t)(c0 + drow) * R + r0 + seg * 8] = o;
        }
        return;
    }

    // ---------- router + layernorm ----------
    // smem layout: floats [0..511] = stats (256 x float2), [512..519] logits,
    //              [520..521] mu/rstd
    int t = q;
    const float* xrow = x + (size_t)t * DDIM;
    float4 xv = ((const float4*)xrow)[tid];
    float s  = xv.x + xv.y + xv.z + xv.w;
    float sq = xv.x * xv.x + xv.y * xv.y + xv.z * xv.z + xv.w * xv.w;
    ((float2*)smem)[tid] = make_float2(s, sq);

    // logits: 32 lanes per expert, lane-strided dims (coalesced scalar loads)
    int e = tid >> 5, l32 = tid & 31;
    const float* wrow = WrT + e * DDIM + l32;
    const float* xp = xrow + l32;
    float a0 = 0, a1 = 0, a2 = 0, a3 = 0;
#pragma unroll
    for (int j = 0; j < 32; j += 4) {
        a0 += xp[32 * j]       * wrow[32 * j];
        a1 += xp[32 * (j + 1)] * wrow[32 * (j + 1)];
        a2 += xp[32 * (j + 2)] * wrow[32 * (j + 2)];
        a3 += xp[32 * (j + 3)] * wrow[32 * (j + 3)];
    }
    float acc = (a0 + a1) + (a2 + a3);
#pragma unroll
    for (int o = 16; o > 0; o >>= 1) acc += __shfl_down(acc, o, 32);
    if ((tid & 31) == 0) smem[512 + e] = acc;
    __syncthreads();

    if (tid < 64) {
        float2 p0 = ((float2*)smem)[tid];
        float2 p1 = ((float2*)smem)[tid + 64];
        float2 p2 = ((float2*)smem)[tid + 128];
        float2 p3 = ((float2*)smem)[tid + 192];
        float ss = (p0.x + p1.x) + (p2.x + p3.x);
        float qq = (p0.y + p1.y) + (p2.y + p3.y);
#pragma unroll
        for (int o = 32; o > 0; o >>= 1) {
            ss += __shfl_down(ss, o);
            qq += __shfl_down(qq, o);
        }
        if (tid == 0) {
            float mu = ss * (1.f / DDIM);
            float var = qq * (1.f / DDIM) - mu * mu;
            float rstd = rsqrtf(var + 1e-5f);
            int best = 0; float bl = -3.4e38f;
            float L[8];
            for (int k = 0; k < 8; k++) {
                float l = smem[512 + k] + br[k];
                L[k] = l;
                if (l > bl) { bl = l; best = k; }   // strict > == jnp.argmax first-max
            }
            float den = 0;
            for (int k = 0; k < 8; k++) den += __expf(L[k] - bl);
            gate[t] = 1.f / den;
            expert[t] = best;
            atomicAdd(&counts[best], 1);
            smem[520] = mu; smem[521] = rstd;
        }
    }
    __syncthreads();
    float mu = smem[520], rstd = smem[521];
    float4 gg = ((const float4*)lng)[tid];
    float4 bb = ((const float4*)lnb)[tid];
    ushort4 o;
    o.x = f2bf((xv.x - mu) * rstd * gg.x + bb.x);
    o.y = f2bf((xv.y - mu) * rstd * gg.y + bb.y);
    o.z = f2bf((xv.z - mu) * rstd * gg.z + bb.z);
    o.w = f2bf((xv.w - mu) * rstd * gg.w + bb.w);
    *(ushort4*)(xn + (size_t)t * DDIM + tid * 4) = o;
}

// ---------------- scatter tokens into per-expert lists (scan folded in) ----
__global__ __launch_bounds__(256) void scatter_perm(
    const int* __restrict__ expert, const int* __restrict__ counts,
    int* __restrict__ fill, int* __restrict__ perm) {
    __shared__ int offs_s[NEXP];
    if (threadIdx.x < NEXP) {
        int o = 0;
        for (int i = 0; i < (int)threadIdx.x; i++) o += counts[i];
        offs_s[threadIdx.x] = o;
    }
    __syncthreads();
    int t = blockIdx.x * 256 + threadIdx.x;
    int e = expert[t];
    int p = atomicAdd(&fill[e], 1);
    perm[offs_s[e] + p] = t;
}

// ---------------- grouped GEMM (m97 structure) ----------------
// MODE 0: h_perm = relu(xn[perm] @ W1t[e]^T + b1[e])  128x128 tile, K=1024
// MODE 1: y[perm] = (h_perm @ W2t[e]^T + b2[e])*gate  128x64 tile,  K=4096
template <int MODE>
__global__ __launch_bounds__(256) void gemm_grouped(
    const unsigned short* __restrict__ A, const unsigned short* __restrict__ Bt,
    const float* __restrict__ bias, unsigned short* __restrict__ Hout,
    float* __restrict__ Yout, const float* __restrict__ gate,
    const int* __restrict__ perm, const int* __restrict__ counts,
    int K, int N) {
    constexpr int BN_ = (MODE == 0) ? 128 : 64;
    constexpr int AI  = (MODE == 0) ? 4 : 2;   // A frags / wave
    constexpr int BROWS = (MODE == 0) ? 2 : 1; // B staging rows / thread

    int rem = blockIdx.x;
    int e, off = 0, cnt = 0; bool found = false;
    for (e = 0; e < NEXP; e++) {
        cnt = counts[e];
        int mt = (cnt + (BM - 1)) >> 7;
        if (rem < mt) { found = true; break; }
        rem -= mt; off += cnt;
    }
    if (!found) return;
    int mbase = rem << 7;
    int mrem = cnt - mbase;
    int n0 = blockIdx.y * BN_;

    __shared__ __align__(16) unsigned short Alds[BM * BK];
    __shared__ __align__(16) unsigned short Blds[BN_ * BK];

    int tid = threadIdx.x;
    int lane = tid & 63, wave = tid >> 6;
    int grow = lane >> 2;         // row within 16-row wave group
    int seg  = lane & 3;          // 16-B segment within 64-B row

    const unsigned short* ag[2];
    unsigned short* al[2];
    const unsigned short* bg[BROWS];
    unsigned short* bl[BROWS];
#pragma unroll
    for (int p = 0; p < 2; p++) {
        int r = p * 64 + wave * 16 + grow;
        int rr = (r < mrem) ? r : 0;
        if (MODE == 0) {
            int t = perm[off + mbase + rr];          // gather token
            ag[p] = A + (size_t)t * K + seg * 8;
        } else {
            ag[p] = A + (size_t)(off + mbase + rr) * K + seg * 8;  // h is permuted
        }
        al[p] = &Alds[(p * 64 + wave * 16) * BK];
    }
#pragma unroll
    for (int p = 0; p < BROWS; p++) {
        int r = p * 64 + wave * 16 + grow;
        bg[p] = Bt + ((size_t)e * N + n0 + r) * K + seg * 8;
        bl[p] = &Blds[(p * 64 + wave * 16) * BK];
    }

    int wr = (MODE == 0) ? (wave >> 1) * 64 : wave * 32;
    int wc = (MODE == 0) ? (wave & 1) * 64 : 0;
    int q = lane >> 4, l16 = lane & 15;

    f32x4 acc[AI][4] = {};

    for (int k0 = 0; k0 < K; k0 += BK) {
#pragma unroll
        for (int p = 0; p < 2; p++) async16(ag[p] + k0, al[p]);
#pragma unroll
        for (int p = 0; p < BROWS; p++) async16(bg[p] + k0, bl[p]);
        __syncthreads();
        bf16x8 af[AI], bfr[4];
#pragma unroll
        for (int i = 0; i < AI; i++)
            af[i] = *(const bf16x8*)&Alds[(wr + i * 16 + l16) * BK + q * 8];
#pragma unroll
        for (int j = 0; j < 4; j++)
            bfr[j] = *(const bf16x8*)&Blds[(wc + j * 16 + l16) * BK + q * 8];
#pragma unroll
        for (int i = 0; i < AI; i++)
#pragma unroll
            for (int j = 0; j < 4; j++)
                acc[i][j] = __builtin_amdgcn_mfma_f32_16x16x32_bf16(af[i], bfr[j], acc[i][j], 0, 0, 0);
        __syncthreads();
    }

    // epilogue: D layout col = lane&15, row = quad*4 + reg (m89/m91)
    float bs[4];
#pragma unroll
    for (int j = 0; j < 4; j++) bs[j] = bias[(size_t)e * N + n0 + wc + j * 16 + l16];
#pragma unroll
    for (int i = 0; i < AI; i++) {
#pragma unroll
        for (int r = 0; r < 4; r++) {
            int lrow = wr + i * 16 + q * 4 + r;
            if (lrow < mrem) {
                if (MODE == 0) {
                    unsigned short* hp = Hout + (size_t)(off + mbase + lrow) * N + n0 + wc + l16;
#pragma unroll
                    for (int j = 0; j < 4; j++) {
                        float v = acc[i][j][r] + bs[j];
                        hp[j * 16] = f2bf(fmaxf(v, 0.f));
                    }
                } else {
                    int t = perm[off + mbase + lrow];
                    float gt = gate[t];
                    float* yp = Yout + (size_t)t * N + n0 + wc + l16;
#pragma unroll
                    for (int j = 0; j < 4; j++)
                        yp[j * 16] = (acc[i][j][r] + bs[j]) * gt;
                }
            }
        }
    }
}

extern "C" void kernel_launch(void* const* d_in, const int* in_sizes, int n_in,
                              void* d_out, int out_size, void* d_ws, size_t ws_size,
                              hipStream_t stream) {
    const float* x   = (const float*)d_in[0];
    const float* Wr  = (const float*)d_in[1];
    const float* br  = (const float*)d_in[2];
    const float* lng = (const float*)d_in[3];
    const float* lnb = (const float*)d_in[4];
    const float* W1  = (const float*)d_in[5];
    const float* b1  = (const float*)d_in[6];
    const float* W2  = (const float*)d_in[7];
    const float* b2  = (const float*)d_in[8];
    float* out = (float*)d_out;

    char* ws = (char*)d_ws;
    size_t o = 0;
    unsigned short* W1t = (unsigned short*)(ws + o); o += (size_t)NEXP * DDIM * FDIM * 2;  // [E][F][D]
    unsigned short* W2t = (unsigned short*)(ws + o); o += (size_t)NEXP * DDIM * FDIM * 2;  // [E][D][F]
    unsigned short* xn  = (unsigned short*)(ws + o); o += (size_t)T_TOK * DDIM * 2;        // [T][D]
    unsigned short* h   = (unsigned short*)(ws + o); o += (size_t)T_TOK * FDIM * 2;        // [Tperm][F]
    float* gate = (float*)(ws + o); o += (size_t)T_TOK * 4;
    float* WrT  = (float*)(ws + o); o += (size_t)NEXP * DDIM * 4;                          // [E][D]
    int* expert = (int*)(ws + o);   o += (size_t)T_TOK * 4;
    int* perm   = (int*)(ws + o);   o += (size_t)T_TOK * 4;
    int* meta   = (int*)(ws + o);   // counts[8], fill[8]
    int* counts = meta;
    int* fill   = meta + 8;

    init_kernel<<<32, 256, 0, stream>>>(Wr, WrT, meta);
    prep<<<3 * T_TOK, 256, 0, stream>>>(x, WrT, br, lng, lnb, W1, W2,
                                        xn, W1t, W2t, gate, expert, counts);
    scatter_perm<<<T_TOK / 256, 256, 0, stream>>>(expert, counts, fill, perm);
    gemm_grouped<0><<<dim3(MAX_MT, FDIM / 128), 256, 0, stream>>>(
        xn, W1t, b1, h, nullptr, nullptr, perm, counts, DDIM, FDIM);
    gemm_grouped<1><<<dim3(MAX_MT, DDIM / 64), 256, 0, stream>>>(
        h, W2t, b2, nullptr, out, gate, perm, counts, FDIM, DDIM);
}

// Round 5
// 618.938 us; speedup vs baseline: 1.3046x; 1.0637x over previous
//
#include <hip/hip_runtime.h>
#include <stdint.h>

#define T_TOK 8192
#define DDIM  1024
#define FDIM  4096
#define NEXP  8
#define BM 128
#define BK 64
#define MAX_MT (T_TOK / BM + NEXP)   // worst-case sum of per-expert M-tiles = 72

typedef __attribute__((ext_vector_type(8))) short bf16x8;
typedef __attribute__((ext_vector_type(8))) unsigned short u16x8;
typedef __attribute__((ext_vector_type(4))) float f32x4;

__device__ __forceinline__ unsigned short f2bf(float f) {
    union { float f; unsigned u; } v; v.f = f;
    unsigned u = v.u;
    u += 0x7fffu + ((u >> 16) & 1u);   // round-to-nearest-even
    return (unsigned short)(u >> 16);
}

__device__ __forceinline__ void async16(const void* g, void* l) {
    __builtin_amdgcn_global_load_lds(
        (const __attribute__((address_space(1))) unsigned int*)g,
        (__attribute__((address_space(3))) unsigned int*)l, 16, 0, 0);
}

// ============ init: zero meta + build WrT[8][1024] (replaces memset) =======
__global__ __launch_bounds__(256) void init_kernel(
    const float* __restrict__ Wr, float* __restrict__ WrT, int* __restrict__ meta) {
    int idx = blockIdx.x * 256 + threadIdx.x;   // 32 blocks x 256 = 8192
    if (idx < 16) meta[idx] = 0;
    float v = Wr[idx];                          // Wr[d][e], d=idx>>3, e=idx&7
    WrT[(idx & 7) * DDIM + (idx >> 3)] = v;
}

// ============ fused prep: blockIdx%3 == 0 router, 1 W1-transpose, 2 W2 =====
__global__ __launch_bounds__(256) void prep(
    const float* __restrict__ x, const float* __restrict__ WrT, const float* __restrict__ br,
    const float* __restrict__ lng, const float* __restrict__ lnb,
    const float* __restrict__ W1, const float* __restrict__ W2,
    unsigned short* __restrict__ xn, unsigned short* __restrict__ W1t,
    unsigned short* __restrict__ W2t, float* __restrict__ gate,
    int* __restrict__ expert, int* __restrict__ counts) {
    __shared__ float smem[64 * 65];
    int b = blockIdx.x, tid = threadIdx.x;
    int r3 = b % 3, q = b / 3;

    if (r3 != 0) {
        // ---------- transpose + fp32->bf16 ----------
        const float* src; unsigned short* dst; int R, C, e, c0, r0;
        if (r3 == 1) {                  // W1 [E][1024][4096] -> W1t [E][4096][1024]
            R = DDIM; C = FDIM;
            e = q >> 10;
            c0 = (q & 63) * 64; r0 = ((q >> 6) & 15) * 64;
            src = W1; dst = W1t;
        } else {                        // W2 [E][4096][1024] -> W2t [E][1024][4096]
            R = FDIM; C = DDIM;
            e = q >> 10;
            c0 = (q & 15) * 64; r0 = ((q >> 4) & 63) * 64;
            src = W2; dst = W2t;
        }
        const float* s = src + (size_t)e * R * C;
        unsigned short* d = dst + (size_t)e * R * C;
        float (*tile)[65] = (float(*)[65])smem;
        int lr = tid >> 4, lc = (tid & 15) * 4;
#pragma unroll
        for (int i = 0; i < 4; i++) {
            float4 v = *(const float4*)&s[(size_t)(r0 + lr + i * 16) * C + c0 + lc];
            tile[lr + i * 16][lc + 0] = v.x;
            tile[lr + i * 16][lc + 1] = v.y;
            tile[lr + i * 16][lc + 2] = v.z;
            tile[lr + i * 16][lc + 3] = v.w;
        }
        __syncthreads();
#pragma unroll
        for (int i = 0; i < 2; i++) {
            int ix = tid + i * 256;
            int drow = ix >> 3, seg = ix & 7;
            u16x8 o;
#pragma unroll
            for (int j = 0; j < 8; j++) o[j] = f2bf(tile[seg * 8 + j][drow]);
            *(u16x8*)&d[(size_t)(c0 + drow) * R + r0 + seg * 8] = o;
        }
        return;
    }

    // ---------- router + layernorm ----------
    int t = q;
    const float* xrow = x + (size_t)t * DDIM;
    float4 xv = ((const float4*)xrow)[tid];
    float s  = xv.x + xv.y + xv.z + xv.w;
    float sq = xv.x * xv.x + xv.y * xv.y + xv.z * xv.z + xv.w * xv.w;
    ((float2*)smem)[tid] = make_float2(s, sq);

    // logits: 32 lanes per expert, lane-strided dims (coalesced scalar loads)
    int e = tid >> 5, l32 = tid & 31;
    const float* wrow = WrT + e * DDIM + l32;
    const float* xp = xrow + l32;
    float a0 = 0, a1 = 0, a2 = 0, a3 = 0;
#pragma unroll
    for (int j = 0; j < 32; j += 4) {
        a0 += xp[32 * j]       * wrow[32 * j];
        a1 += xp[32 * (j + 1)] * wrow[32 * (j + 1)];
        a2 += xp[32 * (j + 2)] * wrow[32 * (j + 2)];
        a3 += xp[32 * (j + 3)] * wrow[32 * (j + 3)];
    }
    float acc = (a0 + a1) + (a2 + a3);
#pragma unroll
    for (int o = 16; o > 0; o >>= 1) acc += __shfl_down(acc, o, 32);
    if ((tid & 31) == 0) smem[512 + e] = acc;
    __syncthreads();

    if (tid < 64) {
        float2 p0 = ((float2*)smem)[tid];
        float2 p1 = ((float2*)smem)[tid + 64];
        float2 p2 = ((float2*)smem)[tid + 128];
        float2 p3 = ((float2*)smem)[tid + 192];
        float ss = (p0.x + p1.x) + (p2.x + p3.x);
        float qq = (p0.y + p1.y) + (p2.y + p3.y);
#pragma unroll
        for (int o = 32; o > 0; o >>= 1) {
            ss += __shfl_down(ss, o);
            qq += __shfl_down(qq, o);
        }
        if (tid == 0) {
            float mu = ss * (1.f / DDIM);
            float var = qq * (1.f / DDIM) - mu * mu;
            float rstd = rsqrtf(var + 1e-5f);
            int best = 0; float bl = -3.4e38f;
            float L[8];
            for (int k = 0; k < 8; k++) {
                float l = smem[512 + k] + br[k];
                L[k] = l;
                if (l > bl) { bl = l; best = k; }   // strict > == jnp.argmax first-max
            }
            float den = 0;
            for (int k = 0; k < 8; k++) den += __expf(L[k] - bl);
            gate[t] = 1.f / den;
            expert[t] = best;
            atomicAdd(&counts[best], 1);
            smem[520] = mu; smem[521] = rstd;
        }
    }
    __syncthreads();
    float mu = smem[520], rstd = smem[521];
    float4 gg = ((const float4*)lng)[tid];
    float4 bb = ((const float4*)lnb)[tid];
    ushort4 o;
    o.x = f2bf((xv.x - mu) * rstd * gg.x + bb.x);
    o.y = f2bf((xv.y - mu) * rstd * gg.y + bb.y);
    o.z = f2bf((xv.z - mu) * rstd * gg.z + bb.z);
    o.w = f2bf((xv.w - mu) * rstd * gg.w + bb.w);
    *(ushort4*)(xn + (size_t)t * DDIM + tid * 4) = o;
}

// ---------------- scatter tokens into per-expert lists (scan folded in) ----
__global__ __launch_bounds__(256) void scatter_perm(
    const int* __restrict__ expert, const int* __restrict__ counts,
    int* __restrict__ fill, int* __restrict__ perm) {
    __shared__ int offs_s[NEXP];
    if (threadIdx.x < NEXP) {
        int o = 0;
        for (int i = 0; i < (int)threadIdx.x; i++) o += counts[i];
        offs_s[threadIdx.x] = o;
    }
    __syncthreads();
    int t = blockIdx.x * 256 + threadIdx.x;
    int e = expert[t];
    int p = atomicAdd(&fill[e], 1);
    perm[offs_s[e] + p] = t;
}

// ---------------- grouped GEMM: BK=64, xor-swizzled LDS ----------------
// LDS[row][s] (s = 16B chunk 0..7) holds global k-chunk s ^ (row&7).
// Staging lane picks global seg = seg ^ grow; frag read at slot c ^ (row&7).
// MODE 0: h_perm = relu(xn[perm] @ W1t[e]^T + b1[e])  128x128 tile, K=1024
// MODE 1: y[perm] = (h_perm @ W2t[e]^T + b2[e])*gate  128x64 tile,  K=4096
template <int MODE>
__global__ __launch_bounds__(256) void gemm_grouped(
    const unsigned short* __restrict__ A, const unsigned short* __restrict__ Bt,
    const float* __restrict__ bias, unsigned short* __restrict__ Hout,
    float* __restrict__ Yout, const float* __restrict__ gate,
    const int* __restrict__ perm, const int* __restrict__ counts,
    int K, int N) {
    constexpr int BN_   = (MODE == 0) ? 128 : 64;
    constexpr int AI    = (MODE == 0) ? 4 : 2;   // A frags / wave
    constexpr int BPASS = (MODE == 0) ? 4 : 2;   // B staging calls / thread

    int rem = blockIdx.x;
    int e, off = 0, cnt = 0; bool found = false;
    for (e = 0; e < NEXP; e++) {
        cnt = counts[e];
        int mt = (cnt + (BM - 1)) >> 7;
        if (rem < mt) { found = true; break; }
        rem -= mt; off += cnt;
    }
    if (!found) return;
    int mbase = rem << 7;
    int mrem = cnt - mbase;
    int n0 = blockIdx.y * BN_;

    __shared__ __align__(16) unsigned short Alds[BM * BK];   // 16 KB
    __shared__ __align__(16) unsigned short Blds[BN_ * BK];  // 16/8 KB

    int tid = threadIdx.x;
    int lane = tid & 63, wave = tid >> 6;
    int grow = lane >> 3;         // 0..7: row within 8-row chunk
    int seg  = lane & 7;          // 0..7: LDS 16B slot within 128B row
    int gseg = seg ^ grow;        // xor-swizzled global k-chunk

    const unsigned short* ag[4];
    unsigned short* al[4];
    const unsigned short* bg[BPASS];
    unsigned short* bl[BPASS];
#pragma unroll
    for (int p = 0; p < 4; p++) {
        int r = p * 32 + wave * 8 + grow;
        int rr = (r < mrem) ? r : 0;
        int t = (MODE == 0) ? perm[off + mbase + rr] : (off + mbase + rr);
        ag[p] = A + (size_t)t * K + gseg * 8;
        al[p] = &Alds[(p * 32 + wave * 8) * BK];   // wave-uniform base
    }
#pragma unroll
    for (int p = 0; p < BPASS; p++) {
        int r = p * 32 + wave * 8 + grow;
        bg[p] = Bt + ((size_t)e * N + n0 + r) * K + gseg * 8;
        bl[p] = &Blds[(p * 32 + wave * 8) * BK];
    }

    int wr = (MODE == 0) ? (wave >> 1) * 64 : wave * 32;
    int wc = (MODE == 0) ? (wave & 1) * 64 : 0;
    int q = lane >> 4, l16 = lane & 15;
    int sx = l16 & 7;             // row&7 for all frag rows this lane touches

    f32x4 acc[AI][4] = {};

    for (int k0 = 0; k0 < K; k0 += BK) {
#pragma unroll
        for (int p = 0; p < 4; p++) async16(ag[p] + k0, al[p]);
#pragma unroll
        for (int p = 0; p < BPASS; p++) async16(bg[p] + k0, bl[p]);
        __syncthreads();
#pragma unroll
        for (int kk = 0; kk < 2; kk++) {
            int slot = ((kk * 4 + q) ^ sx) * 8;
            bf16x8 af[AI], bfr[4];
#pragma unroll
            for (int i = 0; i < AI; i++)
                af[i] = *(const bf16x8*)&Alds[(wr + i * 16 + l16) * BK + slot];
#pragma unroll
            for (int j = 0; j < 4; j++)
                bfr[j] = *(const bf16x8*)&Blds[(wc + j * 16 + l16) * BK + slot];
#pragma unroll
            for (int i = 0; i < AI; i++)
#pragma unroll
                for (int j = 0; j < 4; j++)
                    acc[i][j] = __builtin_amdgcn_mfma_f32_16x16x32_bf16(af[i], bfr[j], acc[i][j], 0, 0, 0);
        }
        __syncthreads();
    }

    // epilogue: D layout col = lane&15, row = quad*4 + reg (m89/m91)
    float bs[4];
#pragma unroll
    for (int j = 0; j < 4; j++) bs[j] = bias[(size_t)e * N + n0 + wc + j * 16 + l16];
#pragma unroll
    for (int i = 0; i < AI; i++) {
#pragma unroll
        for (int r = 0; r < 4; r++) {
            int lrow = wr + i * 16 + q * 4 + r;
            if (lrow < mrem) {
                if (MODE == 0) {
                    unsigned short* hp = Hout + (size_t)(off + mbase + lrow) * N + n0 + wc + l16;
#pragma unroll
                    for (int j = 0; j < 4; j++) {
                        float v = acc[i][j][r] + bs[j];
                        hp[j * 16] = f2bf(fmaxf(v, 0.f));
                    }
                } else {
                    int t = perm[off + mbase + lrow];
                    float gt = gate[t];
                    float* yp = Yout + (size_t)t * N + n0 + wc + l16;
#pragma unroll
                    for (int j = 0; j < 4; j++)
                        yp[j * 16] = (acc[i][j][r] + bs[j]) * gt;
                }
            }
        }
    }
}

extern "C" void kernel_launch(void* const* d_in, const int* in_sizes, int n_in,
                              void* d_out, int out_size, void* d_ws, size_t ws_size,
                              hipStream_t stream) {
    const float* x   = (const float*)d_in[0];
    const float* Wr  = (const float*)d_in[1];
    const float* br  = (const float*)d_in[2];
    const float* lng = (const float*)d_in[3];
    const float* lnb = (const float*)d_in[4];
    const float* W1  = (const float*)d_in[5];
    const float* b1  = (const float*)d_in[6];
    const float* W2  = (const float*)d_in[7];
    const float* b2  = (const float*)d_in[8];
    float* out = (float*)d_out;

    char* ws = (char*)d_ws;
    size_t o = 0;
    unsigned short* W1t = (unsigned short*)(ws + o); o += (size_t)NEXP * DDIM * FDIM * 2;  // [E][F][D]
    unsigned short* W2t = (unsigned short*)(ws + o); o += (size_t)NEXP * DDIM * FDIM * 2;  // [E][D][F]
    unsigned short* xn  = (unsigned short*)(ws + o); o += (size_t)T_TOK * DDIM * 2;        // [T][D]
    unsigned short* h   = (unsigned short*)(ws + o); o += (size_t)T_TOK * FDIM * 2;        // [Tperm][F]
    float* gate = (float*)(ws + o); o += (size_t)T_TOK * 4;
    float* WrT  = (float*)(ws + o); o += (size_t)NEXP * DDIM * 4;                          // [E][D]
    int* expert = (int*)(ws + o);   o += (size_t)T_TOK * 4;
    int* perm   = (int*)(ws + o);   o += (size_t)T_TOK * 4;
    int* meta   = (int*)(ws + o);   // counts[8], fill[8]
    int* counts = meta;
    int* fill   = meta + 8;

    init_kernel<<<32, 256, 0, stream>>>(Wr, WrT, meta);
    prep<<<3 * T_TOK, 256, 0, stream>>>(x, WrT, br, lng, lnb, W1, W2,
                                        xn, W1t, W2t, gate, expert, counts);
    scatter_perm<<<T_TOK / 256, 256, 0, stream>>>(expert, counts, fill, perm);
    gemm_grouped<0><<<dim3(MAX_MT, FDIM / 128), 256, 0, stream>>>(
        xn, W1t, b1, h, nullptr, nullptr, perm, counts, DDIM, FDIM);
    gemm_grouped<1><<<dim3(MAX_MT, DDIM / 64), 256, 0, stream>>>(
        h, W2t, b2, nullptr, out, gate, perm, counts, FDIM, DDIM);
}